// Round 2
// baseline (194.222 us; speedup 1.0000x reference)
//
#include <hip/hip_runtime.h>
#include <math.h>

// Problem constants
#define BN   4
#define CN   256
#define HN   128
#define WN   128
#define COMP 64
#define KK   25      // K*K taps
#define HO   64
#define WO   64

// ---------------- workspace layout (float offsets) ----------------
// wA : 9*16*64*8 bf16 A-fragments = 36864 float slots
// tb : 225 floats (+pad to 256)
// P  : partial logits [BN][HO][4][KK][64] fp32
#define TB_OFF    36864
#define P_OFF     37120
#define P_COUNT   ((size_t)BN * HO * 4 * KK * 64)
#define WS_NEED   ((size_t)(P_OFF + P_COUNT) * 4)

typedef short v8s  __attribute__((ext_vector_type(8)));
typedef float v16f __attribute__((ext_vector_type(16)));

__device__ inline ushort f2bf(float f) {       // fp32 -> bf16 bits, RNE
  unsigned u = __float_as_uint(f);
  return (ushort)((u + 0x7fffu + ((u >> 16) & 1u)) >> 16);
}

// ---------------------------------------------------------------------------
// Compose kernel (36 blocks x 256 thr): wA MFMA A-fragments (bf16) + tb.
// ---------------------------------------------------------------------------
__global__ __launch_bounds__(256) void compose_kernel(
    const float* __restrict__ w1, const float* __restrict__ b1,
    const float* __restrict__ w2, float* __restrict__ ws) {
  const int cid = blockIdx.x;                  // 0..35
  const int tid = threadIdx.x;
  const int t = cid >> 2;                      // 0..8
  const int chunk = (cid & 3) * 4 + (tid >> 6);// 0..15 (16-ch group)
  const int lane = tid & 63;
  const int m = lane & 31, half = lane >> 5;
  const int c0 = chunk * 16 + half * 8;
  float acc[8] = {0.f, 0.f, 0.f, 0.f, 0.f, 0.f, 0.f, 0.f};
  if (m < KK) {
    for (int k = 0; k < COMP; ++k) {
      float wv = w2[(size_t)(m * COMP + k) * 9 + t];
      const float* w1r = w1 + (size_t)k * CN + c0;
      float4 a = *(const float4*)w1r;
      float4 bq = *(const float4*)(w1r + 4);
      acc[0] += wv * a.x;  acc[1] += wv * a.y;
      acc[2] += wv * a.z;  acc[3] += wv * a.w;
      acc[4] += wv * bq.x; acc[5] += wv * bq.y;
      acc[6] += wv * bq.z; acc[7] += wv * bq.w;
    }
  }
  ushort* wA = (ushort*)ws;
  ushort pk[8];
#pragma unroll
  for (int j = 0; j < 8; ++j) pk[j] = f2bf(acc[j]);
  *(ushort4*)(wA + ((size_t)(t * 16 + chunk) * 64 + lane) * 8) =
      make_ushort4(pk[0], pk[1], pk[2], pk[3]);
  *(ushort4*)(wA + ((size_t)(t * 16 + chunk) * 64 + lane) * 8 + 4) =
      make_ushort4(pk[4], pk[5], pk[6], pk[7]);
  if (chunk == 0 && lane < KK) {
    float tbv = 0.f;
    for (int k = 0; k < COMP; ++k)
      tbv += w2[(size_t)(lane * COMP + k) * 9 + t] * b1[k];
    ws[TB_OFF + lane * 9 + t] = tbv;
  }
}

// ---------------------------------------------------------------------------
// conv_partial: grid (HO, BN, 4 chunks) = 1024 blocks, 1024 thr = 16 waves.
// Each block: stage its 64-ch chunk (3 rows, bf16, XOR-swizzled LDS),
// MFMA (kf = wv&3, tapgroup = wv>>2), tree-reduce 16 waves, write 25x64
// fp32 partial logits to ws. VGPR capped at 64 -> 2 blocks/CU resident.
// LDS: stage buf 49152 B aliases red 51200 B (barrier-ordered).
// C/D layout: col(px)=lane&31, row(m)=(reg&3)+8*(reg>>2)+4*(lane>>5).
// ---------------------------------------------------------------------------
__global__ __launch_bounds__(1024, 8) void conv_partial(
    float* __restrict__ ws, const float* __restrict__ x) {
  const int ho = blockIdx.x, b = blockIdx.y, cq = blockIdx.z;
  const int tid = threadIdx.x;
  const int lane = tid & 63;
  const int wv = tid >> 6;                     // 0..15
  const int n = lane & 31, half = lane >> 5;

  __shared__ __attribute__((aligned(16))) char smem[51200];
  float* red = (float*)smem;                   // 8*KK*64 floats

  const ushort* wA = (const ushort*)ws;
  const float* __restrict__ xb = x + (size_t)(b * CN) * (HN * WN);

  // ---- stage chunk cq: 3 rows x 128 px x 64 ch -> bf16 LDS ----
  const int px = tid & 127;                    // 0..127
  const int cg = tid >> 7;                     // 0..7 (8-ch subgroup)
  float sreg[3][8];
#pragma unroll
  for (int dr = 0; dr < 3; ++dr) {
    const int r = 2 * ho + dr - 1;
    if (r >= 0) {                              // block-uniform (ho==0, dr==0)
      const float* xp = xb + ((size_t)(cq * 64 + cg * 8) * HN + r) * WN + px;
#pragma unroll
      for (int i = 0; i < 8; ++i) sreg[dr][i] = xp[(size_t)i * (HN * WN)];
    } else {
#pragma unroll
      for (int i = 0; i < 8; ++i) sreg[dr][i] = 0.f;
    }
  }
#pragma unroll
  for (int dr = 0; dr < 3; ++dr) {
    v8s o;
#pragma unroll
    for (int i = 0; i < 8; ++i) o[i] = (short)f2bf(sreg[dr][i]);
    const int boff = (((dr * 128 + px) * 64 + cg * 8) * 2)
                     ^ (((px >> 1) & 7) << 4);
    *(v8s*)(smem + boff) = o;
  }
  __syncthreads();

  // ---- MFMA ----
  const int kf = wv & 3;                       // 16-ch frag within chunk
  const int tg = wv >> 2;                      // tap group
  const int kidx = cq * 4 + kf;                // global 16-ch group
  const v8s zero8 = {};
  v16f acc[2] = {{}, {}};
#pragma unroll
  for (int t = 0; t < 9; ++t) {
    const int tgt = (t >= 6) ? 3 : (t >> 1);
    if (tgt != tg) continue;                   // wave-uniform
    const int dr = t / 3, dc = t % 3;
    if (2 * ho + dr - 1 < 0) continue;         // block-uniform
    const v8s af = *(const v8s*)(wA + ((size_t)(t * 16 + kidx) * 64 + lane) * 8);
#pragma unroll
    for (int wt = 0; wt < 2; ++wt) {
      const int q = 2 * (wt * 32 + n) + dc - 1;
      const bool bad = q < 0;                  // only lane n==0, wt==0, dc==0
      const int qc = bad ? 0 : q;
      const int boff = (((dr * 128 + qc) * 64 + kf * 16 + half * 8) * 2)
                       ^ (((qc >> 1) & 7) << 4);
      v8s bf = *(const v8s*)(smem + boff);
      if (dc == 0 && bad) bf = zero8;
      acc[wt] = __builtin_amdgcn_mfma_f32_32x32x16_bf16(af, bf, acc[wt], 0, 0, 0);
    }
  }
  __syncthreads();                             // stage reads done; red may alias

  // ---- tree 16 -> 8 -> 4 -> 2 ----
  if (wv >= 8) {
#pragma unroll
    for (int wt = 0; wt < 2; ++wt)
#pragma unroll
      for (int rg = 0; rg < 16; ++rg) {
        int m = (rg & 3) + 8 * (rg >> 2) + 4 * half;
        if (m < KK) red[((wv - 8) * KK + m) * 64 + wt * 32 + n] = acc[wt][rg];
      }
  }
  __syncthreads();
  if (wv < 8) {
#pragma unroll
    for (int wt = 0; wt < 2; ++wt)
#pragma unroll
      for (int rg = 0; rg < 16; ++rg) {
        int m = (rg & 3) + 8 * (rg >> 2) + 4 * half;
        if (m < KK) red[(wv * KK + m) * 64 + wt * 32 + n] += acc[wt][rg];
      }
  }
  __syncthreads();
  if (wv < 4) {
#pragma unroll
    for (int m = 0; m < KK; ++m)
      red[(wv * KK + m) * 64 + lane] += red[((wv + 4) * KK + m) * 64 + lane];
  }
  __syncthreads();
  if (wv < 2) {
#pragma unroll
    for (int m = 0; m < KK; ++m)
      red[(wv * KK + m) * 64 + lane] += red[((wv + 2) * KK + m) * 64 + lane];
  }
  __syncthreads();
  if (tid < 64) {
    float* P = ws + P_OFF + (size_t)(((b * HO + ho) * 4 + cq) * KK) * 64;
#pragma unroll
    for (int m = 0; m < KK; ++m)
      P[m * 64 + lane] =
          red[(0 * KK + m) * 64 + lane] + red[(1 * KK + m) * 64 + lane];
  }
}

// ---------------------------------------------------------------------------
// softmax_gather: grid (HO, BN, 4) = 1024 blocks, 1024 thr = 16 waves.
// Wave0 sums 4 chunk-partials + bias terms -> softmax -> sml LDS.
// All waves prefetch gather loads before the barrier; wave wv gathers
// channels cq*64 + wv*4 .. +3 (4 ci iterations, 2-deep prefetch ring).
// ---------------------------------------------------------------------------
__global__ __launch_bounds__(1024, 8) void softmax_gather(
    const float* __restrict__ ws, const float* __restrict__ b2,
    const float* __restrict__ x, float* __restrict__ out) {
  const int ho = blockIdx.x, b = blockIdx.y, cq = blockIdx.z;
  const int tid = threadIdx.x;
  const int lane = tid & 63;
  const int wv = tid >> 6;                     // 0..15

  __shared__ float sml[KK * 64];               // 6400 B

  const float* __restrict__ xb = x + (size_t)(b * CN) * (HN * WN);
  const int wo = lane;
  const int c_base = __builtin_amdgcn_readfirstlane(cq * 64 + wv * 4);
  const int col = 2 * wo;
  float2 g[2][5];
  auto load_g = [&](int ci, float2* dst) {
    const float* xc = xb + (size_t)(c_base + ci) * (HN * WN);
#pragma unroll
    for (int i = 0; i < 5; ++i) {
      int r = 2 * ho - 2 + i;
      dst[i] = (r >= 0 && r < HN) ? *(const float2*)(xc + r * WN + col)
                                  : make_float2(0.f, 0.f);
    }
  };
  load_g(0, g[0]);
  load_g(1, g[1]);

  if (tid < 64) {
    const float* tb = ws + TB_OFF;
    const float* P = ws + P_OFF + (size_t)((b * HO + ho) * 4) * KK * 64;
    const float vr0 = (ho > 0) ? 1.f : 0.f;
    const float vq0 = (wo > 0) ? 1.f : 0.f;
    float logit[KK];
    float mx = -1e30f;
#pragma unroll
    for (int m = 0; m < KK; ++m) {
      const float* t9 = tb + m * 9;
      float l = b2[m]
              + vr0 * (vq0 * t9[0] + t9[1] + t9[2])
              +       (vq0 * t9[3] + t9[4] + t9[5])
              +       (vq0 * t9[6] + t9[7] + t9[8]);
      l += P[(0 * KK + m) * 64 + wo] + P[(1 * KK + m) * 64 + wo]
         + P[(2 * KK + m) * 64 + wo] + P[(3 * KK + m) * 64 + wo];
      logit[m] = l;
      mx = fmaxf(mx, l);
    }
    float ssum = 0.f;
#pragma unroll
    for (int m = 0; m < KK; ++m) {
      float e = __expf(logit[m] - mx);
      logit[m] = e;
      ssum += e;
    }
    float inv = 1.f / ssum;
#pragma unroll
    for (int m = 0; m < KK; ++m) sml[m * 64 + wo] = logit[m] * inv;
  }
  __syncthreads();

  float smr[KK];
#pragma unroll
  for (int m = 0; m < KK; ++m) smr[m] = sml[m * 64 + wo];

  const float wok = (wo > 0) ? 1.f : 0.f;
  const float w63 = (wo < 63) ? 1.f : 0.f;
  for (int ci = 0; ci < 4; ++ci) {
    float2 v[5];
#pragma unroll
    for (int i = 0; i < 5; ++i) v[i] = g[ci & 1][i];
    if (ci + 2 < 4) load_g(ci + 2, g[ci & 1]);

    float acc2 = 0.f;
#pragma unroll
    for (int i = 0; i < 5; ++i) {
      float lx = wok * __shfl_up(v[i].x, 1, 64);    // col 2wo-2
      float ly = wok * __shfl_up(v[i].y, 1, 64);    // col 2wo-1
      float rx = w63 * __shfl_down(v[i].x, 1, 64);  // col 2wo+2
      acc2 += lx * smr[i * 5 + 0] + ly * smr[i * 5 + 1]
            + v[i].x * smr[i * 5 + 2] + v[i].y * smr[i * 5 + 3]
            + rx * smr[i * 5 + 4];
    }
    out[(((size_t)(b * CN + c_base + ci)) * HO + ho) * WO + wo] = acc2;
  }
}

// ============================ FALLBACK PATH ================================
// Round-2 proven kernels (used only if ws_size < WS_NEED).
#define FB_WSTRIDE 240
#define FB_TB_OFF  (256 * FB_WSTRIDE)

__global__ __launch_bounds__(256) void compose_w_fb(
    const float* __restrict__ w1, const float* __restrict__ b1,
    const float* __restrict__ w2, float* __restrict__ ws) {
  int mt = blockIdx.x, c = threadIdx.x;
  float acc = 0.f;
#pragma unroll 8
  for (int k = 0; k < COMP; ++k)
    acc += w2[(size_t)(mt / 9 * COMP + k) * 9 + (mt % 9)] * w1[k * CN + c];
  ws[c * FB_WSTRIDE + mt] = acc;
  if (mt < FB_WSTRIDE - 225) ws[c * FB_WSTRIDE + 225 + mt] = 0.f;
  if (c == 0) {
    float tbv = 0.f;
    for (int k = 0; k < COMP; ++k)
      tbv += w2[(size_t)(mt / 9 * COMP + k) * 9 + (mt % 9)] * b1[k];
    ws[FB_TB_OFF + mt] = tbv;
  }
}

__global__ __launch_bounds__(1024, 4) void fused_fb(
    const float* __restrict__ x, const float* __restrict__ b2,
    const float* __restrict__ ws, float* __restrict__ out) {
  const int ho = blockIdx.x, b = blockIdx.y, tid = threadIdx.x;
  const int wo = tid & 63, wv = tid >> 6;
  const int c_base = __builtin_amdgcn_readfirstlane(wv * 16);
  const float* __restrict__ w2c = ws;
  const float* __restrict__ tb  = ws + FB_TB_OFF;
  __shared__ float red[8 * KK * 64];
  __shared__ float sm[KK * 64];
  const float* __restrict__ xb = x + (size_t)(b * CN) * (HN * WN);
  const int col = 2 * wo;
  float acc[KK];
#pragma unroll
  for (int m = 0; m < KK; ++m) acc[m] = 0.f;
  float2 xbuf[2][3];
  auto load_ch = [&](int ci, float2* dst) {
    const float* xc = xb + (size_t)(c_base + ci) * (HN * WN);
    dst[0] = (ho > 0) ? *(const float2*)(xc + (2 * ho - 1) * WN + col)
                      : make_float2(0.f, 0.f);
    dst[1] = *(const float2*)(xc + (2 * ho) * WN + col);
    dst[2] = *(const float2*)(xc + (2 * ho + 1) * WN + col);
  };
  load_ch(0, xbuf[0]);
  load_ch(1, xbuf[1]);
  const float wok = (wo > 0) ? 1.f : 0.f;
  for (int ci = 0; ci < 16; ++ci) {
    float2 r0 = xbuf[ci & 1][0], r1 = xbuf[ci & 1][1], r2 = xbuf[ci & 1][2];
    if (ci + 2 < 16) load_ch(ci + 2, xbuf[ci & 1]);
    float xv[9];
    xv[0] = wok * __shfl_up(r0.y, 1, 64); xv[1] = r0.x; xv[2] = r0.y;
    xv[3] = wok * __shfl_up(r1.y, 1, 64); xv[4] = r1.x; xv[5] = r1.y;
    xv[6] = wok * __shfl_up(r2.y, 1, 64); xv[7] = r2.x; xv[8] = r2.y;
    const float* __restrict__ wrow = w2c + (size_t)(c_base + ci) * FB_WSTRIDE;
#pragma unroll
    for (int m = 0; m < KK; ++m) {
      float a = acc[m];
#pragma unroll
      for (int t = 0; t < 9; ++t) a += wrow[m * 9 + t] * xv[t];
      acc[m] = a;
    }
  }
  float2 g[2][5];
  auto load_g = [&](int ci, float2* dst) {
    const float* xc = xb + (size_t)(c_base + ci) * (HN * WN);
#pragma unroll
    for (int i = 0; i < 5; ++i) {
      int r = 2 * ho - 2 + i;
      dst[i] = (r >= 0 && r < HN) ? *(const float2*)(xc + r * WN + col)
                                  : make_float2(0.f, 0.f);
    }
  };
  load_g(0, g[0]);
  load_g(1, g[1]);
  if (wv >= 8) {
#pragma unroll
    for (int m = 0; m < KK; ++m) red[((wv - 8) * KK + m) * 64 + wo] = acc[m];
  }
  __syncthreads();
  if (wv < 8) {
#pragma unroll
    for (int m = 0; m < KK; ++m) red[(wv * KK + m) * 64 + wo] += acc[m];
  }
  __syncthreads();
  if (wv < 4) {
#pragma unroll
    for (int m = 0; m < KK; ++m)
      red[(wv * KK + m) * 64 + wo] += red[((wv + 4) * KK + m) * 64 + wo];
  }
  __syncthreads();
  if (wv < 2) {
#pragma unroll
    for (int m = 0; m < KK; ++m)
      red[(wv * KK + m) * 64 + wo] += red[((wv + 2) * KK + m) * 64 + wo];
  }
  __syncthreads();
  if (tid < 64) {
    const float vr0 = (ho > 0) ? 1.f : 0.f;
    const float vq0 = (wo > 0) ? 1.f : 0.f;
    float logit[KK];
    float mx = -1e30f;
#pragma unroll
    for (int m = 0; m < KK; ++m) {
      const float* t9 = tb + m * 9;
      float l = b2[m]
              + vr0 * (vq0 * t9[0] + t9[1] + t9[2])
              +       (vq0 * t9[3] + t9[4] + t9[5])
              +       (vq0 * t9[6] + t9[7] + t9[8]);
      l += red[(0 * KK + m) * 64 + wo] + red[(1 * KK + m) * 64 + wo];
      logit[m] = l;
      mx = fmaxf(mx, l);
    }
    float s = 0.f;
#pragma unroll
    for (int m = 0; m < KK; ++m) {
      float e = __expf(logit[m] - mx);
      logit[m] = e;
      s += e;
    }
    float inv = 1.f / s;
#pragma unroll
    for (int m = 0; m < KK; ++m) sm[m * 64 + wo] = logit[m] * inv;
  }
  __syncthreads();
  float smr[KK];
#pragma unroll
  for (int m = 0; m < KK; ++m) smr[m] = sm[m * 64 + wo];
  const float w63 = (wo < 63) ? 1.f : 0.f;
  for (int ci = 0; ci < 16; ++ci) {
    float2 v[5];
#pragma unroll
    for (int i = 0; i < 5; ++i) v[i] = g[ci & 1][i];
    if (ci + 2 < 16) load_g(ci + 2, g[ci & 1]);
    float acc2 = 0.f;
#pragma unroll
    for (int i = 0; i < 5; ++i) {
      float lx = wok * __shfl_up(v[i].x, 1, 64);
      float ly = wok * __shfl_up(v[i].y, 1, 64);
      float rx = w63 * __shfl_down(v[i].x, 1, 64);
      acc2 += lx * smr[i * 5 + 0] + ly * smr[i * 5 + 1]
            + v[i].x * smr[i * 5 + 2] + v[i].y * smr[i * 5 + 3]
            + rx * smr[i * 5 + 4];
    }
    out[(((size_t)(b * CN + c_base + ci)) * HO + ho) * WO + wo] = acc2;
  }
}

// ---------------------------------------------------------------------------
extern "C" void kernel_launch(void* const* d_in, const int* in_sizes, int n_in,
                              void* d_out, int out_size, void* d_ws, size_t ws_size,
                              hipStream_t stream) {
  const float* x  = (const float*)d_in[0];
  const float* w1 = (const float*)d_in[1];
  const float* b1 = (const float*)d_in[2];
  const float* w2 = (const float*)d_in[3];
  const float* b2 = (const float*)d_in[4];
  float* out = (float*)d_out;
  float* ws  = (float*)d_ws;

  if (ws_size >= WS_NEED) {
    hipLaunchKernelGGL(compose_kernel, dim3(36), dim3(256), 0, stream,
                       w1, b1, w2, ws);
    hipLaunchKernelGGL(conv_partial, dim3(HO, BN, 4), dim3(1024), 0, stream,
                       ws, x);
    hipLaunchKernelGGL(softmax_gather, dim3(HO, BN, 4), dim3(1024), 0, stream,
                       ws, b2, x, out);
  } else {
    hipLaunchKernelGGL(compose_w_fb, dim3(225), dim3(256), 0, stream,
                       w1, b1, w2, ws);
    hipLaunchKernelGGL(fused_fb, dim3(HO, BN), dim3(1024), 0, stream,
                       x, b2, ws, out);
  }
}

// Round 3
// 167.086 us; speedup vs baseline: 1.1624x; 1.1624x over previous
//
#include <hip/hip_runtime.h>
#include <math.h>

// Problem constants
#define BN   4
#define CN   256
#define HN   128
#define WN   128
#define COMP 64
#define KK   25      // K*K taps
#define HO   64
#define WO   64

// ---------------- workspace layout (float offsets) ----------------
// wA : 9*16*64*8 bf16 A-fragments = 36864 float slots
// tb : 225 floats (+pad to 256)
#define TB_OFF    36864
#define WS_NEED   ((size_t)(TB_OFF + 256) * 4)

typedef short v8s  __attribute__((ext_vector_type(8)));
typedef float v16f __attribute__((ext_vector_type(16)));

__device__ inline ushort f2bf(float f) {       // fp32 -> bf16 bits, RNE
  unsigned u = __float_as_uint(f);
  return (ushort)((u + 0x7fffu + ((u >> 16) & 1u)) >> 16);
}

// ---------------------------------------------------------------------------
// Compose kernel (36 blocks x 256 thr): wA MFMA A-fragments (bf16) + tb.
// ---------------------------------------------------------------------------
__global__ __launch_bounds__(256) void compose_kernel(
    const float* __restrict__ w1, const float* __restrict__ b1,
    const float* __restrict__ w2, float* __restrict__ ws) {
  const int cid = blockIdx.x;                  // 0..35
  const int tid = threadIdx.x;
  const int t = cid >> 2;                      // 0..8
  const int chunk = (cid & 3) * 4 + (tid >> 6);// 0..15 (16-ch group)
  const int lane = tid & 63;
  const int m = lane & 31, half = lane >> 5;
  const int c0 = chunk * 16 + half * 8;
  float acc[8] = {0.f, 0.f, 0.f, 0.f, 0.f, 0.f, 0.f, 0.f};
  if (m < KK) {
    for (int k = 0; k < COMP; ++k) {
      float wv = w2[(size_t)(m * COMP + k) * 9 + t];
      const float* w1r = w1 + (size_t)k * CN + c0;
      float4 a = *(const float4*)w1r;
      float4 bq = *(const float4*)(w1r + 4);
      acc[0] += wv * a.x;  acc[1] += wv * a.y;
      acc[2] += wv * a.z;  acc[3] += wv * a.w;
      acc[4] += wv * bq.x; acc[5] += wv * bq.y;
      acc[6] += wv * bq.z; acc[7] += wv * bq.w;
    }
  }
  ushort* wA = (ushort*)ws;
  ushort pk[8];
#pragma unroll
  for (int j = 0; j < 8; ++j) pk[j] = f2bf(acc[j]);
  *(ushort4*)(wA + ((size_t)(t * 16 + chunk) * 64 + lane) * 8) =
      make_ushort4(pk[0], pk[1], pk[2], pk[3]);
  *(ushort4*)(wA + ((size_t)(t * 16 + chunk) * 64 + lane) * 8 + 4) =
      make_ushort4(pk[4], pk[5], pk[6], pk[7]);
  if (chunk == 0 && lane < KK) {
    float tbv = 0.f;
    for (int k = 0; k < COMP; ++k)
      tbv += w2[(size_t)(lane * COMP + k) * 9 + t] * b1[k];
    ws[TB_OFF + lane * 9 + t] = tbv;
  }
}

// ---------------------------------------------------------------------------
// fused_half: grid (HO, BN, 2 col-halves) = 512 blocks -> 2 blocks/CU.
// Block h owns output cols [32h, 32h+32).
// Stage: 4 chunks x 64ch, rows 2ho-1..2ho+1, px S0=64h-4 .. +72 (apron incl.
//   left-pad zeros staged -> no bad-lane fix in MFMA). bf16, XOR-swizzled.
// MFMA: 16 waves = kf(0..3) x tapgroup(0..3), ONE 32-col tile each.
// Tree 16->8->4->2 in red[8][25][32]; softmax by tid<32 -> sml.
// Gather: 64-lane waves, lo=lane&31 (col), su=lane>>5 (8-ch subgroup);
//   width-32 shuffles; 3 boundary cols per half pre-staged in LDS edge buf
//   (zero-filled where masked -> no NaN*0).
// LDS: stage 27648 B (aliases red 25600) + sml 3200 + edges 15360 = 46208 B.
// launch_bounds(1024,4): the known-good-codegen config (R1 -> 64 VGPR).
//   (1024,8) makes hipcc cap VGPR=32 and spill (R2 post-mortem).
// ---------------------------------------------------------------------------
#define SML_OFF 27648
#define EL_OFF  30848
#define ER_OFF  41088
#define LDS_SZ  46208

__global__ __launch_bounds__(1024, 4) void fused_half(
    const float* __restrict__ ws, const float* __restrict__ b2,
    const float* __restrict__ x, float* __restrict__ out) {
  const int ho = blockIdx.x, b = blockIdx.y, h = blockIdx.z;
  const int tid = threadIdx.x;
  const int lane = tid & 63;
  const int wv = tid >> 6;                     // 0..15
  const int n = lane & 31, half = lane >> 5;   // MFMA col / k-half (= lo/su)

  __shared__ __attribute__((aligned(16))) char smem[LDS_SZ];
  float* red = (float*)smem;                   // 8*25*32 fp32 = 25600 B
  float* sml = (float*)(smem + SML_OFF);       // 25*32 fp32   =  3200 B

  const ushort* wA = (const ushort*)ws;
  const float* __restrict__ xb = x + (size_t)(b * CN) * (HN * WN);

  // ---------------- staging (regs) ----------------
  const int p = tid & 127;                     // staged px index 0..127 (<72 used)
  const int cg = tid >> 7;                     // 0..7 (8-ch subgroup)
  const int q = 64 * h - 4 + p;                // global input col
  const bool pok = (p < 72) && (q >= 0) && (q < WN);
  float sreg[3][8];

  auto stage_load = [&](int c) {
#pragma unroll
    for (int dr = 0; dr < 3; ++dr) {
      const int r = 2 * ho + dr - 1;
      if (pok && r >= 0) {
        const float* xp = xb + ((size_t)(c * 64 + cg * 8) * HN + r) * WN + q;
#pragma unroll
        for (int i = 0; i < 8; ++i) sreg[dr][i] = xp[(size_t)i * (HN * WN)];
      } else {
#pragma unroll
        for (int i = 0; i < 8; ++i) sreg[dr][i] = 0.f;
      }
    }
  };
  auto stage_write = [&]() {
    if (p < 72) {
#pragma unroll
      for (int dr = 0; dr < 3; ++dr) {
        v8s o;
#pragma unroll
        for (int i = 0; i < 8; ++i) o[i] = (short)f2bf(sreg[dr][i]);
        const int boff = (((dr * 72 + p) * 64 + cg * 8) * 2)
                         ^ (((p >> 1) & 7) << 4);
        *(v8s*)(smem + boff) = o;
      }
    }
  };

  // ---------------- Phase 1: conv via MFMA over 4 ch-chunks ----------------
  const int kf = wv & 3;                       // 16-ch frag within chunk
  const int tg = wv >> 2;                      // tap group
  const int t0 = (tg < 3) ? 2 * tg : 6;
  const int ntap = (tg < 3) ? 2 : 3;
  v16f acc = {};

  stage_load(0);
  for (int c = 0; c < 4; ++c) {
    __syncthreads();                           // LDS free (prev chunk read)
    stage_write();
    const int kidx = c * 4 + kf;               // global 16-ch group
    v8s afr[3];
#pragma unroll
    for (int tt = 0; tt < 3; ++tt)             // A-frags: global, overlap write
      if (tt < ntap)
        afr[tt] = *(const v8s*)(wA + ((size_t)((t0 + tt) * 16 + kidx) * 64 + lane) * 8);
    __syncthreads();                           // LDS ready
    if (c < 3) stage_load(c + 1);              // next loads fly under MFMA
#pragma unroll
    for (int tt = 0; tt < 3; ++tt) {
      if (tt >= ntap) continue;                // wave-uniform
      const int t = t0 + tt;
      const int dr = t / 3, dc = t % 3;
      if (2 * ho + dr - 1 < 0) continue;       // block+wave-uniform (ho==0)
      const int pb = 2 * n + dc + 3;           // staged px of input col
      const int boff = (((dr * 72 + pb) * 64 + kf * 16 + half * 8) * 2)
                       ^ (((pb >> 1) & 7) << 4);
      v8s bf = *(const v8s*)(smem + boff);
      acc = __builtin_amdgcn_mfma_f32_32x32x16_bf16(afr[tt], bf, acc, 0, 0, 0);
    }
  }

  // ------- prefetch gather loads + stage edge cols (fly during tree) -------
  const int lo = n;                            // output col within half
  const int oc = 32 * h + lo;                  // global output col
  const int colb = 64 * h + 2 * lo;            // main input col pair base
  float2 g[2][5];
  auto load_g = [&](int ci, float2* dst) {
    const float* xc = xb + (size_t)(wv * 16 + half * 8 + ci) * (HN * WN);
#pragma unroll
    for (int i = 0; i < 5; ++i) {
      int r = 2 * ho - 2 + i;
      dst[i] = (r >= 0 && r < HN) ? *(const float2*)(xc + r * WN + colb)
                                  : make_float2(0.f, 0.f);
    }
  };
  load_g(0, g[0]);
  load_g(1, g[1]);

  {                                            // edge buffer: 3 cols x 5 rows x 256 ch
    float* eLf = (float*)(smem + EL_OFF);
    float* eRf = (float*)(smem + ER_OFF);
#pragma unroll
    for (int it = 0; it < 2; ++it) {
      const int idx = it * 1024 + tid;         // 0..2047
      const int ch = idx >> 3, sl = idx & 7;
      if (sl < 5) {
        const int r = 2 * ho - 2 + sl;
        float2 lv = make_float2(0.f, 0.f);
        float rv = 0.f;
        if (r >= 0 && r < HN) {
          const float* xc = xb + (size_t)ch * (HN * WN) + (size_t)r * WN;
          if (h == 1) lv = *(const float2*)(xc + 62);   // cols 62,63
          else        rv = xc[64];                       // col 64
        }
        *(float2*)(eLf + (ch * 5 + sl) * 2) = lv;
        eRf[ch * 5 + sl] = rv;
      }
    }
  }

  __syncthreads();                             // stage buf -> red transition

  // ---------------- Reduction 16 -> 8 -> 4 -> 2, then softmax --------------
  if (wv >= 8) {
#pragma unroll
    for (int rg = 0; rg < 16; ++rg) {
      int m = (rg & 3) + 8 * (rg >> 2) + 4 * half;
      if (m < KK) red[((wv - 8) * KK + m) * 32 + n] = acc[rg];
    }
  }
  __syncthreads();
  if (wv < 8) {
#pragma unroll
    for (int rg = 0; rg < 16; ++rg) {
      int m = (rg & 3) + 8 * (rg >> 2) + 4 * half;
      if (m < KK) red[(wv * KK + m) * 32 + n] += acc[rg];
    }
  }
  __syncthreads();
  if (wv < 4) {
#pragma unroll 13
    for (int m = half; m < KK; m += 2)
      red[(wv * KK + m) * 32 + n] += red[((wv + 4) * KK + m) * 32 + n];
  }
  __syncthreads();
  if (wv < 2) {
#pragma unroll 13
    for (int m = half; m < KK; m += 2)
      red[(wv * KK + m) * 32 + n] += red[((wv + 2) * KK + m) * 32 + n];
  }
  __syncthreads();
  if (tid < 32) {
    const float* tb = ws + TB_OFF;
    const int wo32 = tid;
    const int occ = 32 * h + wo32;
    const float vr0 = (ho > 0) ? 1.f : 0.f;
    const float vq0 = (occ > 0) ? 1.f : 0.f;
    float logit[KK];
    float mx = -1e30f;
#pragma unroll
    for (int m = 0; m < KK; ++m) {
      const float* t9 = tb + m * 9;
      float l = b2[m]
              + vr0 * (vq0 * t9[0] + t9[1] + t9[2])
              +       (vq0 * t9[3] + t9[4] + t9[5])
              +       (vq0 * t9[6] + t9[7] + t9[8]);
      l += red[(0 * KK + m) * 32 + wo32] + red[(1 * KK + m) * 32 + wo32];
      logit[m] = l;
      mx = fmaxf(mx, l);
    }
    float ssum = 0.f;
#pragma unroll
    for (int m = 0; m < KK; ++m) {
      float e = __expf(logit[m] - mx);
      logit[m] = e;
      ssum += e;
    }
    float inv = 1.f / ssum;
#pragma unroll
    for (int m = 0; m < KK; ++m) sml[m * 32 + wo32] = logit[m] * inv;
  }
  __syncthreads();

  // ---------------- Phase 2: CARAFE gather (32-col half) ----------------
  float smr[KK];
#pragma unroll
  for (int m = 0; m < KK; ++m) smr[m] = sml[m * 32 + lo];

  const float* eLf = (const float*)(smem + EL_OFF);
  const float* eRf = (const float*)(smem + ER_OFF);
  const float wok = (oc > 0) ? 1.f : 0.f;
  const float w63 = (oc < 63) ? 1.f : 0.f;
#pragma unroll
  for (int ci = 0; ci < 8; ++ci) {
    const int ch = wv * 16 + half * 8 + ci;
    float2 v[5];
#pragma unroll
    for (int i = 0; i < 5; ++i) v[i] = g[ci & 1][i];
    if (ci + 2 < 8) load_g(ci + 2, g[ci & 1]);

    float acc2 = 0.f;
#pragma unroll
    for (int i = 0; i < 5; ++i) {
      const float2 elv = *(const float2*)(eLf + (ch * 5 + i) * 2);
      const float erv = eRf[ch * 5 + i];
      float lxs = __shfl_up(v[i].x, 1, 32);    // col 2oc-2
      float lys = __shfl_up(v[i].y, 1, 32);    // col 2oc-1
      float rxs = __shfl_down(v[i].x, 1, 32);  // col 2oc+2
      if (lo == 0)  { lxs = elv.x; lys = elv.y; }
      if (lo == 31) { rxs = erv; }
      acc2 += wok * (lxs * smr[i * 5 + 0] + lys * smr[i * 5 + 1])
            + v[i].x * smr[i * 5 + 2] + v[i].y * smr[i * 5 + 3]
            + w63 * rxs * smr[i * 5 + 4];
    }
    out[(((size_t)(b * CN + ch)) * HO + ho) * WO + oc] = acc2;
  }
}

// ============================ FALLBACK PATH ================================
// Round-2 proven kernels (used only if ws_size < WS_NEED).
#define FB_WSTRIDE 240
#define FB_TB_OFF  (256 * FB_WSTRIDE)

__global__ __launch_bounds__(256) void compose_w_fb(
    const float* __restrict__ w1, const float* __restrict__ b1,
    const float* __restrict__ w2, float* __restrict__ ws) {
  int mt = blockIdx.x, c = threadIdx.x;
  float acc = 0.f;
#pragma unroll 8
  for (int k = 0; k < COMP; ++k)
    acc += w2[(size_t)(mt / 9 * COMP + k) * 9 + (mt % 9)] * w1[k * CN + c];
  ws[c * FB_WSTRIDE + mt] = acc;
  if (mt < FB_WSTRIDE - 225) ws[c * FB_WSTRIDE + 225 + mt] = 0.f;
  if (c == 0) {
    float tbv = 0.f;
    for (int k = 0; k < COMP; ++k)
      tbv += w2[(size_t)(mt / 9 * COMP + k) * 9 + (mt % 9)] * b1[k];
    ws[FB_TB_OFF + mt] = tbv;
  }
}

__global__ __launch_bounds__(1024, 4) void fused_fb(
    const float* __restrict__ x, const float* __restrict__ b2,
    const float* __restrict__ ws, float* __restrict__ out) {
  const int ho = blockIdx.x, b = blockIdx.y, tid = threadIdx.x;
  const int wo = tid & 63, wv = tid >> 6;
  const int c_base = __builtin_amdgcn_readfirstlane(wv * 16);
  const float* __restrict__ w2c = ws;
  const float* __restrict__ tb  = ws + FB_TB_OFF;
  __shared__ float red[8 * KK * 64];
  __shared__ float sm[KK * 64];
  const float* __restrict__ xb = x + (size_t)(b * CN) * (HN * WN);
  const int col = 2 * wo;
  float acc[KK];
#pragma unroll
  for (int m = 0; m < KK; ++m) acc[m] = 0.f;
  float2 xbuf[2][3];
  auto load_ch = [&](int ci, float2* dst) {
    const float* xc = xb + (size_t)(c_base + ci) * (HN * WN);
    dst[0] = (ho > 0) ? *(const float2*)(xc + (2 * ho - 1) * WN + col)
                      : make_float2(0.f, 0.f);
    dst[1] = *(const float2*)(xc + (2 * ho) * WN + col);
    dst[2] = *(const float2*)(xc + (2 * ho + 1) * WN + col);
  };
  load_ch(0, xbuf[0]);
  load_ch(1, xbuf[1]);
  const float wok = (wo > 0) ? 1.f : 0.f;
  for (int ci = 0; ci < 16; ++ci) {
    float2 r0 = xbuf[ci & 1][0], r1 = xbuf[ci & 1][1], r2 = xbuf[ci & 1][2];
    if (ci + 2 < 16) load_ch(ci + 2, xbuf[ci & 1]);
    float xv[9];
    xv[0] = wok * __shfl_up(r0.y, 1, 64); xv[1] = r0.x; xv[2] = r0.y;
    xv[3] = wok * __shfl_up(r1.y, 1, 64); xv[4] = r1.x; xv[5] = r1.y;
    xv[6] = wok * __shfl_up(r2.y, 1, 64); xv[7] = r2.x; xv[8] = r2.y;
    const float* __restrict__ wrow = w2c + (size_t)(c_base + ci) * FB_WSTRIDE;
#pragma unroll
    for (int m = 0; m < KK; ++m) {
      float a = acc[m];
#pragma unroll
      for (int t = 0; t < 9; ++t) a += wrow[m * 9 + t] * xv[t];
      acc[m] = a;
    }
  }
  float2 g[2][5];
  auto load_g = [&](int ci, float2* dst) {
    const float* xc = xb + (size_t)(c_base + ci) * (HN * WN);
#pragma unroll
    for (int i = 0; i < 5; ++i) {
      int r = 2 * ho - 2 + i;
      dst[i] = (r >= 0 && r < HN) ? *(const float2*)(xc + r * WN + col)
                                  : make_float2(0.f, 0.f);
    }
  };
  load_g(0, g[0]);
  load_g(1, g[1]);
  if (wv >= 8) {
#pragma unroll
    for (int m = 0; m < KK; ++m) red[((wv - 8) * KK + m) * 64 + wo] = acc[m];
  }
  __syncthreads();
  if (wv < 8) {
#pragma unroll
    for (int m = 0; m < KK; ++m) red[(wv * KK + m) * 64 + wo] += acc[m];
  }
  __syncthreads();
  if (wv < 4) {
#pragma unroll
    for (int m = 0; m < KK; ++m)
      red[(wv * KK + m) * 64 + wo] += red[((wv + 4) * KK + m) * 64 + wo];
  }
  __syncthreads();
  if (wv < 2) {
#pragma unroll
    for (int m = 0; m < KK; ++m)
      red[(wv * KK + m) * 64 + wo] += red[((wv + 2) * KK + m) * 64 + wo];
  }
  __syncthreads();
  if (tid < 64) {
    const float vr0 = (ho > 0) ? 1.f : 0.f;
    const float vq0 = (wo > 0) ? 1.f : 0.f;
    float logit[KK];
    float mx = -1e30f;
#pragma unroll
    for (int m = 0; m < KK; ++m) {
      const float* t9 = tb + m * 9;
      float l = b2[m]
              + vr0 * (vq0 * t9[0] + t9[1] + t9[2])
              +       (vq0 * t9[3] + t9[4] + t9[5])
              +       (vq0 * t9[6] + t9[7] + t9[8]);
      l += red[(0 * KK + m) * 64 + wo] + red[(1 * KK + m) * 64 + wo];
      logit[m] = l;
      mx = fmaxf(mx, l);
    }
    float s = 0.f;
#pragma unroll
    for (int m = 0; m < KK; ++m) {
      float e = __expf(logit[m] - mx);
      logit[m] = e;
      s += e;
    }
    float inv = 1.f / s;
#pragma unroll
    for (int m = 0; m < KK; ++m) sm[m * 64 + wo] = logit[m] * inv;
  }
  __syncthreads();
  float smr[KK];
#pragma unroll
  for (int m = 0; m < KK; ++m) smr[m] = sm[m * 64 + wo];
  const float w63 = (wo < 63) ? 1.f : 0.f;
  for (int ci = 0; ci < 16; ++ci) {
    float2 v[5];
#pragma unroll
    for (int i = 0; i < 5; ++i) v[i] = g[ci & 1][i];
    if (ci + 2 < 16) load_g(ci + 2, g[ci & 1]);
    float acc2 = 0.f;
#pragma unroll
    for (int i = 0; i < 5; ++i) {
      float lx = wok * __shfl_up(v[i].x, 1, 64);
      float ly = wok * __shfl_up(v[i].y, 1, 64);
      float rx = w63 * __shfl_down(v[i].x, 1, 64);
      acc2 += lx * smr[i * 5 + 0] + ly * smr[i * 5 + 1]
            + v[i].x * smr[i * 5 + 2] + v[i].y * smr[i * 5 + 3]
            + rx * smr[i * 5 + 4];
    }
    out[(((size_t)(b * CN + c_base + ci)) * HO + ho) * WO + wo] = acc2;
  }
}

// ---------------------------------------------------------------------------
extern "C" void kernel_launch(void* const* d_in, const int* in_sizes, int n_in,
                              void* d_out, int out_size, void* d_ws, size_t ws_size,
                              hipStream_t stream) {
  const float* x  = (const float*)d_in[0];
  const float* w1 = (const float*)d_in[1];
  const float* b1 = (const float*)d_in[2];
  const float* w2 = (const float*)d_in[3];
  const float* b2 = (const float*)d_in[4];
  float* out = (float*)d_out;
  float* ws  = (float*)d_ws;

  if (ws_size >= WS_NEED) {
    hipLaunchKernelGGL(compose_kernel, dim3(36), dim3(256), 0, stream,
                       w1, b1, w2, ws);
    hipLaunchKernelGGL(fused_half, dim3(HO, BN, 2), dim3(1024), 0, stream,
                       ws, b2, x, out);
  } else {
    hipLaunchKernelGGL(compose_w_fb, dim3(225), dim3(256), 0, stream,
                       w1, b1, w2, ws);
    hipLaunchKernelGGL(fused_fb, dim3(HO, BN), dim3(1024), 0, stream,
                       x, b2, ws, out);
  }
}

// Round 4
// 147.638 us; speedup vs baseline: 1.3155x; 1.1317x over previous
//
#include <hip/hip_runtime.h>
#include <math.h>

// Problem constants
#define BN   4
#define CN   256
#define HN   128
#define WN   128
#define COMP 64
#define KK   25      // K*K taps
#define HO   64
#define WO   64

// ---------------- workspace layout (float offsets) ----------------
// w1B  : 16 kidx x 2 nt x 64 lane x 8 bf16  = 16384 u16 = 8192 float slots
// w2A  : 9 t x 4 kidx x 64 lane x 8 bf16    = 18432 u16 = 9216 float slots
// mask : BN*HO*KK*64 fp32                    = 409600 floats
// comp : BN*HN*WN*COMP bf16                  = 4194304 u16 = 2097152 slots
#define W1B_OFF  0
#define W2A_OFF  8192
#define MASK_OFF 17408
#define COMP_OFF 427008
#define WS_NEED  ((size_t)(COMP_OFF + (size_t)BN * HN * WN * COMP / 2) * 4)

typedef short v8s  __attribute__((ext_vector_type(8)));
typedef float v16f __attribute__((ext_vector_type(16)));

__device__ inline ushort f2bf(float f) {       // fp32 -> bf16 bits, RNE
  unsigned u = __float_as_uint(f);
  return (ushort)((u + 0x7fffu + ((u >> 16) & 1u)) >> 16);
}

// ---------------------------------------------------------------------------
// compose_frags: 68 blocks x 64 thr.
//  bid<32 : w1B B-fragments for compress GEMM.  frag(kidx 0..15, nt 0..1):
//           lane holds w1[ch = nt*32+(lane&31)][c = kidx*16+(lane>>5)*8 + j]
//  bid>=32: w2A A-fragments for mask conv. frag(t 0..8, kidx 0..3):
//           lane holds w2[m=(lane&31)][k = kidx*16+(lane>>5)*8+j][t] (m<25)
// ---------------------------------------------------------------------------
__global__ __launch_bounds__(64) void compose_frags(
    const float* __restrict__ w1, const float* __restrict__ w2,
    float* __restrict__ ws) {
  const int bid = blockIdx.x;
  const int lane = threadIdx.x;
  const int k0 = (lane >> 5) * 8;
  ushort pk[8];
  ushort* dst;
  if (bid < 32) {
    const int kidx = bid >> 1, nt = bid & 1;
    const int ch = nt * 32 + (lane & 31);
    const int c0 = kidx * 16 + k0;
#pragma unroll
    for (int j = 0; j < 8; ++j) pk[j] = f2bf(w1[(size_t)ch * CN + c0 + j]);
    dst = (ushort*)(ws + W1B_OFF) + ((size_t)((kidx * 2 + nt) * 64 + lane)) * 8;
  } else {
    const int g = bid - 32;
    const int t = g >> 2, kidx = g & 3;
    const int m = lane & 31;
    const int kk0 = kidx * 16 + k0;
#pragma unroll
    for (int j = 0; j < 8; ++j) {
      float v = (m < KK) ? w2[((size_t)(m * COMP + kk0 + j)) * 9 + t] : 0.f;
      pk[j] = f2bf(v);
    }
    dst = (ushort*)(ws + W2A_OFF) + ((size_t)((t * 4 + kidx) * 64 + lane)) * 8;
  }
  *(ushort4*)(dst)     = make_ushort4(pk[0], pk[1], pk[2], pk[3]);
  *(ushort4*)(dst + 4) = make_ushort4(pk[4], pk[5], pk[6], pk[7]);
}

// ---------------------------------------------------------------------------
// compress: comp[b][h][px][ch] = bf16( w1 . x + b1 ).  grid (HN, BN) x 256thr.
// Pure MFMA GEMM, no LDS, no barriers. Wave w owns px-tile w (m = px).
// A[m=px][k=c] gathered from global x (strided scalar loads, 256B/instr);
// B[k=c][n=ch] = precomposed w1B frags (L2-resident).
// D layout: col(ch)=lane&31, row(px)=(reg&3)+8*(reg>>2)+4*(lane>>5).
// ---------------------------------------------------------------------------
__global__ __launch_bounds__(256, 4) void compress_kernel(
    const float* __restrict__ x, const float* __restrict__ b1,
    float* __restrict__ ws) {
  const int h = blockIdx.x, b = blockIdx.y;
  const int tid = threadIdx.x;
  const int lane = tid & 63, w = tid >> 6;
  const int nn = lane & 31, kh = lane >> 5;
  const int px = w * 32 + nn;
  const ushort* w1B = (const ushort*)(ws + W1B_OFF);
  v16f acc[2] = {{}, {}};
#pragma unroll 2
  for (int kidx = 0; kidx < 16; ++kidx) {
    const float* xc = x + (((size_t)(b * CN + kidx * 16 + kh * 8)) * HN + h) * WN + px;
    float av[8];
#pragma unroll
    for (int j = 0; j < 8; ++j) av[j] = xc[(size_t)j * (HN * WN)];
    v8s af;
#pragma unroll
    for (int j = 0; j < 8; ++j) af[j] = (short)f2bf(av[j]);
    v8s bf0 = *(const v8s*)(w1B + ((size_t)((kidx * 2 + 0) * 64 + lane)) * 8);
    v8s bf1 = *(const v8s*)(w1B + ((size_t)((kidx * 2 + 1) * 64 + lane)) * 8);
    acc[0] = __builtin_amdgcn_mfma_f32_32x32x16_bf16(af, bf0, acc[0], 0, 0, 0);
    acc[1] = __builtin_amdgcn_mfma_f32_32x32x16_bf16(af, bf1, acc[1], 0, 0, 0);
  }
  ushort* comp = (ushort*)(ws + COMP_OFF);
  const size_t rowbase = (size_t)(b * HN + h) * WN;
#pragma unroll
  for (int nt = 0; nt < 2; ++nt) {
    const float bias = b1[nt * 32 + nn];
#pragma unroll
    for (int rg = 0; rg < 16; ++rg) {
      const int pr = w * 32 + (rg & 3) + 8 * (rg >> 2) + 4 * kh;
      comp[(rowbase + pr) * COMP + nt * 32 + nn] = f2bf(acc[nt][rg] + bias);
    }
  }
}

// ---------------------------------------------------------------------------
// mask_softmax: grid (HO, BN) x 256 thr (4 waves).
// Stage comp rows 2ho-1..2ho+1 (zero-fill r<0 == reference ENC_PAD) into
// XOR-swizzled LDS [3][128][64] bf16 (raw copy, already bf16/k-contig).
// Wave w: nt = w&1 (px tile), kh2 = w>>1 (K half); 9 taps x 2 kidx = 18 MFMA.
// 2-way LDS reduce over kh2, then 64-thread softmax -> mask fp32 in ws.
// bad-lane: q=-1 (dc==0, col 0) -> zero B-frag (proven cndmask pattern).
// LDS: 49152 B stage; red (6400 B) aliases it after a barrier.
// ---------------------------------------------------------------------------
#define MS_LDS 49152
__global__ __launch_bounds__(256, 4) void mask_softmax(
    const float* __restrict__ b2, float* __restrict__ ws) {
  const int ho = blockIdx.x, b = blockIdx.y;
  const int tid = threadIdx.x;
  const int lane = tid & 63, w = tid >> 6;
  __shared__ __attribute__((aligned(16))) char smem[MS_LDS];
  float* red = (float*)smem;                   // alias after barrier
  const ushort* comp = (const ushort*)(ws + COMP_OFF);

  // ---- stage 3 rows (3*128*8 = 3072 v8s) ----
#pragma unroll
  for (int i = 0; i < 12; ++i) {
    const int flat = i * 256 + tid;            // 0..3071
    const int r = flat >> 10;                  // 0..2
    const int px = (flat >> 3) & 127;
    const int cg = flat & 7;
    const int rr = 2 * ho + r - 1;
    v8s v = {};
    if (rr >= 0)
      v = *(const v8s*)(comp + ((size_t)(b * HN + rr) * WN + px) * COMP + cg * 8);
    const int boff = (((r * 128 + px) * 64 + cg * 8) * 2) ^ (((px >> 1) & 7) << 4);
    *(v8s*)(smem + boff) = v;
  }
  __syncthreads();

  // ---- MFMA ----
  const int nt = w & 1, kh2 = w >> 1;
  const int nn = lane & 31;
  const ushort* w2A = (const ushort*)(ws + W2A_OFF);
  const v8s zero8 = {};
  v16f acc = {};
#pragma unroll
  for (int t = 0; t < 9; ++t) {
    const int dr = t / 3, dc = t % 3;
#pragma unroll
    for (int ki = 0; ki < 2; ++ki) {
      const int kidx = kh2 * 2 + ki;
      const v8s af = *(const v8s*)(w2A + ((size_t)((t * 4 + kidx) * 64 + lane)) * 8);
      const int q = 2 * (nt * 32 + nn) + dc - 1;
      const bool bad = q < 0;                  // only nt==0, nn==0, dc==0
      const int qc = bad ? 0 : q;
      const int boff = (((dr * 128 + qc) * 64 + kidx * 16 + (lane >> 5) * 8) * 2)
                       ^ (((qc >> 1) & 7) << 4);
      v8s bf = *(const v8s*)(smem + boff);
      if (dc == 0 && bad) bf = zero8;
      acc = __builtin_amdgcn_mfma_f32_32x32x16_bf16(af, bf, acc, 0, 0, 0);
    }
  }
  __syncthreads();                             // stage reads done; red aliases

  // ---- reduce over kh2 ----
  if (kh2 == 1) {
#pragma unroll
    for (int rg = 0; rg < 16; ++rg) {
      const int m = (rg & 3) + 8 * (rg >> 2) + 4 * (lane >> 5);
      if (m < KK) red[(nt * KK + m) * 32 + nn] = acc[rg];
    }
  }
  __syncthreads();
  if (kh2 == 0) {
#pragma unroll
    for (int rg = 0; rg < 16; ++rg) {
      const int m = (rg & 3) + 8 * (rg >> 2) + 4 * (lane >> 5);
      if (m < KK) red[(nt * KK + m) * 32 + nn] += acc[rg];
    }
  }
  __syncthreads();

  // ---- softmax (64 threads, one per wo) ----
  if (tid < 64) {
    const int wo = tid;
    const int tnt = wo >> 5, tc = wo & 31;
    float logit[KK];
    float mx = -1e30f;
#pragma unroll
    for (int m = 0; m < KK; ++m) {
      float l = b2[m] + red[(tnt * KK + m) * 32 + tc];
      logit[m] = l;
      mx = fmaxf(mx, l);
    }
    float ssum = 0.f;
#pragma unroll
    for (int m = 0; m < KK; ++m) {
      float e = __expf(logit[m] - mx);
      logit[m] = e;
      ssum += e;
    }
    const float inv = 1.f / ssum;
    float* mdst = ws + MASK_OFF + (size_t)(b * HO + ho) * KK * 64;
#pragma unroll
    for (int m = 0; m < KK; ++m) mdst[m * 64 + wo] = logit[m] * inv;
  }
}

// ---------------------------------------------------------------------------
// gather: 1024 blocks x 256 thr (4 waves, ~8 blocks/CU).
// Work index XCD-swizzled so each XCD sweeps contiguous ho (L2 row reuse).
// Block: (b, cq, ho); wave wv gathers 16 ch; exact R1-proven gather body.
// ---------------------------------------------------------------------------
__global__ __launch_bounds__(256, 4) void gather_kernel(
    const float* __restrict__ ws, const float* __restrict__ x,
    float* __restrict__ out) {
  const int bid0 = blockIdx.x;
  const int bid = (bid0 & 7) * 128 + (bid0 >> 3);   // bijective (1024 = 8*128)
  const int ho = bid & 63;
  const int cq = (bid >> 6) & 3;
  const int b = bid >> 8;
  const int tid = threadIdx.x;
  const int lane = tid & 63, wv = tid >> 6;

  __shared__ float sml[KK * 64];               // 6400 B

  const float* __restrict__ xb = x + (size_t)(b * CN) * (HN * WN);
  const int wo = lane;
  const int c_base = __builtin_amdgcn_readfirstlane(cq * 64 + wv * 16);
  const int col = 2 * wo;
  float2 g[2][5];
  auto load_g = [&](int ci, float2* dst) {
    const float* xc = xb + (size_t)(c_base + ci) * (HN * WN);
#pragma unroll
    for (int i = 0; i < 5; ++i) {
      int r = 2 * ho - 2 + i;
      dst[i] = (r >= 0 && r < HN) ? *(const float2*)(xc + r * WN + col)
                                  : make_float2(0.f, 0.f);
    }
  };
  load_g(0, g[0]);
  load_g(1, g[1]);

  const float* msrc = ws + MASK_OFF + (size_t)(b * HO + ho) * KK * 64;
  for (int i = tid; i < KK * 64; i += 256) sml[i] = msrc[i];
  __syncthreads();

  float smr[KK];
#pragma unroll
  for (int m = 0; m < KK; ++m) smr[m] = sml[m * 64 + wo];

  const float wok = (wo > 0) ? 1.f : 0.f;
  const float w63 = (wo < 63) ? 1.f : 0.f;
  for (int ci = 0; ci < 16; ++ci) {
    float2 v[5];
#pragma unroll
    for (int i = 0; i < 5; ++i) v[i] = g[ci & 1][i];
    if (ci + 2 < 16) load_g(ci + 2, g[ci & 1]);

    float acc2 = 0.f;
#pragma unroll
    for (int i = 0; i < 5; ++i) {
      float lx = wok * __shfl_up(v[i].x, 1, 64);    // col 2wo-2
      float ly = wok * __shfl_up(v[i].y, 1, 64);    // col 2wo-1
      float rx = w63 * __shfl_down(v[i].x, 1, 64);  // col 2wo+2
      acc2 += lx * smr[i * 5 + 0] + ly * smr[i * 5 + 1]
            + v[i].x * smr[i * 5 + 2] + v[i].y * smr[i * 5 + 3]
            + rx * smr[i * 5 + 4];
    }
    out[(((size_t)(b * CN + c_base + ci)) * HO + ho) * WO + wo] = acc2;
  }
}

// ============================ FALLBACK PATH ================================
// Round-2 proven kernels (used only if ws_size < WS_NEED).
#define FB_WSTRIDE 240
#define FB_TB_OFF  (256 * FB_WSTRIDE)

__global__ __launch_bounds__(256) void compose_w_fb(
    const float* __restrict__ w1, const float* __restrict__ b1,
    const float* __restrict__ w2, float* __restrict__ ws) {
  int mt = blockIdx.x, c = threadIdx.x;
  float acc = 0.f;
#pragma unroll 8
  for (int k = 0; k < COMP; ++k)
    acc += w2[(size_t)(mt / 9 * COMP + k) * 9 + (mt % 9)] * w1[k * CN + c];
  ws[c * FB_WSTRIDE + mt] = acc;
  if (mt < FB_WSTRIDE - 225) ws[c * FB_WSTRIDE + 225 + mt] = 0.f;
  if (c == 0) {
    float tbv = 0.f;
    for (int k = 0; k < COMP; ++k)
      tbv += w2[(size_t)(mt / 9 * COMP + k) * 9 + (mt % 9)] * b1[k];
    ws[FB_TB_OFF + mt] = tbv;
  }
}

__global__ __launch_bounds__(1024, 4) void fused_fb(
    const float* __restrict__ x, const float* __restrict__ b2,
    const float* __restrict__ ws, float* __restrict__ out) {
  const int ho = blockIdx.x, b = blockIdx.y, tid = threadIdx.x;
  const int wo = tid & 63, wv = tid >> 6;
  const int c_base = __builtin_amdgcn_readfirstlane(wv * 16);
  const float* __restrict__ w2c = ws;
  const float* __restrict__ tb  = ws + FB_TB_OFF;
  __shared__ float red[8 * KK * 64];
  __shared__ float sm[KK * 64];
  const float* __restrict__ xb = x + (size_t)(b * CN) * (HN * WN);
  const int col = 2 * wo;
  float acc[KK];
#pragma unroll
  for (int m = 0; m < KK; ++m) acc[m] = 0.f;
  float2 xbuf[2][3];
  auto load_ch = [&](int ci, float2* dst) {
    const float* xc = xb + (size_t)(c_base + ci) * (HN * WN);
    dst[0] = (ho > 0) ? *(const float2*)(xc + (2 * ho - 1) * WN + col)
                      : make_float2(0.f, 0.f);
    dst[1] = *(const float2*)(xc + (2 * ho) * WN + col);
    dst[2] = *(const float2*)(xc + (2 * ho + 1) * WN + col);
  };
  load_ch(0, xbuf[0]);
  load_ch(1, xbuf[1]);
  const float wok = (wo > 0) ? 1.f : 0.f;
  for (int ci = 0; ci < 16; ++ci) {
    float2 r0 = xbuf[ci & 1][0], r1 = xbuf[ci & 1][1], r2 = xbuf[ci & 1][2];
    if (ci + 2 < 16) load_ch(ci + 2, xbuf[ci & 1]);
    float xv[9];
    xv[0] = wok * __shfl_up(r0.y, 1, 64); xv[1] = r0.x; xv[2] = r0.y;
    xv[3] = wok * __shfl_up(r1.y, 1, 64); xv[4] = r1.x; xv[5] = r1.y;
    xv[6] = wok * __shfl_up(r2.y, 1, 64); xv[7] = r2.x; xv[8] = r2.y;
    const float* __restrict__ wrow = w2c + (size_t)(c_base + ci) * FB_WSTRIDE;
#pragma unroll
    for (int m = 0; m < KK; ++m) {
      float a = acc[m];
#pragma unroll
      for (int t = 0; t < 9; ++t) a += wrow[m * 9 + t] * xv[t];
      acc[m] = a;
    }
  }
  float2 g[2][5];
  auto load_g = [&](int ci, float2* dst) {
    const float* xc = xb + (size_t)(c_base + ci) * (HN * WN);
#pragma unroll
    for (int i = 0; i < 5; ++i) {
      int r = 2 * ho - 2 + i;
      dst[i] = (r >= 0 && r < HN) ? *(const float2*)(xc + r * WN + col)
                                  : make_float2(0.f, 0.f);
    }
  };
  load_g(0, g[0]);
  load_g(1, g[1]);
  if (wv >= 8) {
#pragma unroll
    for (int m = 0; m < KK; ++m) red[((wv - 8) * KK + m) * 64 + wo] = acc[m];
  }
  __syncthreads();
  if (wv < 8) {
#pragma unroll
    for (int m = 0; m < KK; ++m) red[(wv * KK + m) * 64 + wo] += acc[m];
  }
  __syncthreads();
  if (wv < 4) {
#pragma unroll
    for (int m = 0; m < KK; ++m)
      red[(wv * KK + m) * 64 + wo] += red[((wv + 4) * KK + m) * 64 + wo];
  }
  __syncthreads();
  if (wv < 2) {
#pragma unroll
    for (int m = 0; m < KK; ++m)
      red[(wv * KK + m) * 64 + wo] += red[((wv + 2) * KK + m) * 64 + wo];
  }
  __syncthreads();
  if (tid < 64) {
    const float vr0 = (ho > 0) ? 1.f : 0.f;
    const float vq0 = (wo > 0) ? 1.f : 0.f;
    float logit[KK];
    float mx = -1e30f;
#pragma unroll
    for (int m = 0; m < KK; ++m) {
      const float* t9 = tb + m * 9;
      float l = b2[m]
              + vr0 * (vq0 * t9[0] + t9[1] + t9[2])
              +       (vq0 * t9[3] + t9[4] + t9[5])
              +       (vq0 * t9[6] + t9[7] + t9[8]);
      l += red[(0 * KK + m) * 64 + wo] + red[(1 * KK + m) * 64 + wo];
      logit[m] = l;
      mx = fmaxf(mx, l);
    }
    float s = 0.f;
#pragma unroll
    for (int m = 0; m < KK; ++m) {
      float e = __expf(logit[m] - mx);
      logit[m] = e;
      s += e;
    }
    float inv = 1.f / s;
#pragma unroll
    for (int m = 0; m < KK; ++m) sm[m * 64 + wo] = logit[m] * inv;
  }
  __syncthreads();
  float smr[KK];
#pragma unroll
  for (int m = 0; m < KK; ++m) smr[m] = sm[m * 64 + wo];
  const float w63 = (wo < 63) ? 1.f : 0.f;
  for (int ci = 0; ci < 16; ++ci) {
    float2 v[5];
#pragma unroll
    for (int i = 0; i < 5; ++i) v[i] = g[ci & 1][i];
    if (ci + 2 < 16) load_g(ci + 2, g[ci & 1]);
    float acc2 = 0.f;
#pragma unroll
    for (int i = 0; i < 5; ++i) {
      float lx = wok * __shfl_up(v[i].x, 1, 64);
      float ly = wok * __shfl_up(v[i].y, 1, 64);
      float rx = w63 * __shfl_down(v[i].x, 1, 64);
      acc2 += lx * smr[i * 5 + 0] + ly * smr[i * 5 + 1]
            + v[i].x * smr[i * 5 + 2] + v[i].y * smr[i * 5 + 3]
            + rx * smr[i * 5 + 4];
    }
    out[(((size_t)(b * CN + c_base + ci)) * HO + ho) * WO + wo] = acc2;
  }
}

// ---------------------------------------------------------------------------
extern "C" void kernel_launch(void* const* d_in, const int* in_sizes, int n_in,
                              void* d_out, int out_size, void* d_ws, size_t ws_size,
                              hipStream_t stream) {
  const float* x  = (const float*)d_in[0];
  const float* w1 = (const float*)d_in[1];
  const float* b1 = (const float*)d_in[2];
  const float* w2 = (const float*)d_in[3];
  const float* b2 = (const float*)d_in[4];
  float* out = (float*)d_out;
  float* ws  = (float*)d_ws;

  if (ws_size >= WS_NEED) {
    hipLaunchKernelGGL(compose_frags, dim3(68), dim3(64), 0, stream,
                       w1, w2, ws);
    hipLaunchKernelGGL(compress_kernel, dim3(HN, BN), dim3(256), 0, stream,
                       x, b1, ws);
    hipLaunchKernelGGL(mask_softmax, dim3(HO, BN), dim3(256), 0, stream,
                       b2, ws);
    hipLaunchKernelGGL(gather_kernel, dim3(1024), dim3(256), 0, stream,
                       ws, x, out);
  } else {
    hipLaunchKernelGGL(compose_w_fb, dim3(225), dim3(256), 0, stream,
                       w1, b1, w2, ws);
    hipLaunchKernelGGL(fused_fb, dim3(HO, BN), dim3(1024), 0, stream,
                       x, b2, ws, out);
  }
}